// Round 1
// baseline (1718.248 us; speedup 1.0000x reference)
//
#include <hip/hip_runtime.h>

#define B_   8
#define C_   512
#define CQ_  64
#define H_   96
#define W_   96
#define HW_  (H_*W_)
#define NPIX_ (B_*HW_)

typedef unsigned short u16;

__device__ __forceinline__ float bf2f(u16 u) {
  unsigned int x = ((unsigned int)u) << 16;
  return __uint_as_float(x);
}
__device__ __forceinline__ u16 f2bf(float f) {
  unsigned int x = __float_as_uint(f);
  x += 0x7fffu + ((x >> 16) & 1u);   // RNE
  return (u16)(x >> 16);
}
__device__ __forceinline__ void store_val(float* p, float v) { *p = v; }
__device__ __forceinline__ void store_val(u16* p, float v)   { *p = f2bf(v); }

// ---------------- projection GEMM: out[b, n, m] = sum_c W[m,c]*x[b,c,n] + bias[m]
// grid (HW/64, M/64, B), 256 threads, 64x64 tile, BK=16
template<typename OutT>
__global__ __launch_bounds__(256) void proj_kernel(
    const float* __restrict__ x, const float* __restrict__ Wm,
    const float* __restrict__ bias, OutT* __restrict__ outp, int M)
{
  const int n0 = blockIdx.x * 64;
  const int m0 = blockIdx.y * 64;
  const int b  = blockIdx.z;
  __shared__ float smem[64*65];
  float* As = smem;          // [64][17]
  float* Bs = smem + 64*17;  // [16][64]
  const int t  = threadIdx.x;
  const int ty = t >> 4, tx = t & 15;
  float acc[4][4] = {};
  const float* xb = x + (size_t)b * C_ * HW_;
  for (int k0 = 0; k0 < C_; k0 += 16) {
    {
      const int i = t >> 2, kk4 = (t & 3) * 4;
      float4 w4 = *(const float4*)(Wm + (size_t)(m0 + i) * C_ + k0 + kk4);
      float* dst = As + i*17 + kk4;
      dst[0]=w4.x; dst[1]=w4.y; dst[2]=w4.z; dst[3]=w4.w;
    }
    {
      const int kk = t >> 4, j4 = (t & 15) * 4;
      float4 b4 = *(const float4*)(xb + (size_t)(k0 + kk) * HW_ + n0 + j4);
      *(float4*)(Bs + kk*64 + j4) = b4;
    }
    __syncthreads();
#pragma unroll
    for (int kk = 0; kk < 16; ++kk) {
      float ar[4], br[4];
#pragma unroll
      for (int i = 0; i < 4; ++i) ar[i] = As[(ty*4+i)*17 + kk];
#pragma unroll
      for (int j = 0; j < 4; ++j) br[j] = Bs[kk*64 + tx*4 + j];
#pragma unroll
      for (int i = 0; i < 4; ++i)
#pragma unroll
        for (int j = 0; j < 4; ++j)
          acc[i][j] = fmaf(ar[i], br[j], acc[i][j]);
    }
    __syncthreads();
  }
  // transpose through LDS for coalesced stores
  float* tile = smem; // [64][65]
#pragma unroll
  for (int i = 0; i < 4; ++i)
#pragma unroll
    for (int j = 0; j < 4; ++j)
      tile[(tx*4+j)*65 + ty*4+i] = acc[i][j];
  __syncthreads();
  for (int r = 0; r < 16; ++r) {
    int lin = r*256 + t;
    int nl = lin >> 6, ml = lin & 63;
    float v = tile[nl*65 + ml] + bias[m0 + ml];
    store_val(outp + (size_t)(b*HW_ + n0 + nl) * M + m0 + ml, v);
  }
}

// ---------------- eH logits: block per (w, b). eH[h,p] = dot64(q[.,h,w], k[.,p,w]); diag -> -inf
__global__ __launch_bounds__(256) void score_col_kernel(
    const float* __restrict__ qp, const float* __restrict__ kp, float* __restrict__ att)
{
  const int w = blockIdx.x, b = blockIdx.y;
  __shared__ float qs[96*68];
  __shared__ float ks[96*68];
  const int t = threadIdx.x;
  for (int r = 0; r < 6; ++r) {
    int f = r*256 + t;                 // 1536 float4s
    int p = f >> 4, c4 = (f & 15) * 4;
    int pix = b*HW_ + p*W_ + w;
    *(float4*)(qs + p*68 + c4) = *(const float4*)(qp + (size_t)pix*CQ_ + c4);
    *(float4*)(ks + p*68 + c4) = *(const float4*)(kp + (size_t)pix*CQ_ + c4);
  }
  __syncthreads();
  const int ty = t >> 4, tx = t & 15;
  float e[6][6] = {};
#pragma unroll 8
  for (int c = 0; c < 64; ++c) {
    float qv[6], kv[6];
#pragma unroll
    for (int a = 0; a < 6; ++a) qv[a] = qs[(ty*6+a)*68 + c];
#pragma unroll
    for (int bb = 0; bb < 6; ++bb) kv[bb] = ks[(tx*6+bb)*68 + c];
#pragma unroll
    for (int a = 0; a < 6; ++a)
#pragma unroll
      for (int bb = 0; bb < 6; ++bb)
        e[a][bb] = fmaf(qv[a], kv[bb], e[a][bb]);
  }
#pragma unroll
  for (int a = 0; a < 6; ++a) {
    int h = ty*6 + a;
    size_t base = ((size_t)(b*H_ + h)*W_ + w) * 192;
#pragma unroll
    for (int bb = 0; bb < 6; ++bb) {
      int p = tx*6 + bb;
      att[base + p] = (h == p) ? -INFINITY : e[a][bb];
    }
  }
}

// ---------------- eW logits: block per (h, b). eW[w,p] = dot64(q[.,h,w], k[.,h,p])
__global__ __launch_bounds__(256) void score_row_kernel(
    const float* __restrict__ qp, const float* __restrict__ kp, float* __restrict__ att)
{
  const int h = blockIdx.x, b = blockIdx.y;
  __shared__ float qs[96*68];
  __shared__ float ks[96*68];
  const int t = threadIdx.x;
  const size_t rowbase = (size_t)(b*HW_ + h*W_) * CQ_;
  for (int r = 0; r < 6; ++r) {
    int f = r*256 + t;
    int wl = f >> 4, c4 = (f & 15) * 4;
    *(float4*)(qs + wl*68 + c4) = *(const float4*)(qp + rowbase + (size_t)wl*CQ_ + c4);
    *(float4*)(ks + wl*68 + c4) = *(const float4*)(kp + rowbase + (size_t)wl*CQ_ + c4);
  }
  __syncthreads();
  const int ty = t >> 4, tx = t & 15;
  float e[6][6] = {};
#pragma unroll 8
  for (int c = 0; c < 64; ++c) {
    float qv[6], kv[6];
#pragma unroll
    for (int a = 0; a < 6; ++a) qv[a] = qs[(ty*6+a)*68 + c];
#pragma unroll
    for (int bb = 0; bb < 6; ++bb) kv[bb] = ks[(tx*6+bb)*68 + c];
#pragma unroll
    for (int a = 0; a < 6; ++a)
#pragma unroll
      for (int bb = 0; bb < 6; ++bb)
        e[a][bb] = fmaf(qv[a], kv[bb], e[a][bb]);
  }
#pragma unroll
  for (int a = 0; a < 6; ++a) {
    int w = ty*6 + a;
    size_t base = ((size_t)(b*H_ + h)*W_ + w) * 192 + 96;
#pragma unroll
    for (int bb = 0; bb < 6; ++bb)
      att[base + tx*6 + bb] = e[a][bb];
  }
}

// ---------------- softmax over 192 logits per pixel; one wave per pixel
__global__ __launch_bounds__(256) void softmax_kernel(float* __restrict__ att)
{
  const int lane = threadIdx.x & 63;
  const int wv   = threadIdx.x >> 6;
  const size_t pix = (size_t)blockIdx.x * 4 + wv;
  float* row = att + pix * 192;
  float v0 = row[lane], v1 = row[lane+64], v2 = row[lane+128];
  float m = fmaxf(v0, fmaxf(v1, v2));
#pragma unroll
  for (int off = 32; off > 0; off >>= 1) m = fmaxf(m, __shfl_xor(m, off, 64));
  float e0 = __expf(v0 - m), e1 = __expf(v1 - m), e2 = __expf(v2 - m);
  float s = e0 + e1 + e2;
#pragma unroll
  for (int off = 32; off > 0; off >>= 1) s += __shfl_xor(s, off, 64);
  float inv = __frcp_rn(s);
  row[lane]     = e0 * inv;
  row[lane+64]  = e1 * inv;
  row[lane+128] = e2 * inv;
}

// ---------------- outH: block per (w, c_tile, b). out = gamma * sum_p attH[h,p]*v[c,p,w]
__global__ __launch_bounds__(256) void outH_kernel(
    const float* __restrict__ att, const u16* __restrict__ vp,
    const float* __restrict__ gammap, float* __restrict__ out)
{
  const int w = blockIdx.x, c0 = blockIdx.y * 128, b = blockIdx.z;
  __shared__ float as_[96*100];  // [h][p]
  __shared__ float vs[16*128];   // [pp][c]
  const int t = threadIdx.x;
  const int ty = t >> 4, tx = t & 15;
  for (int r = 0; r < 9; ++r) {
    int f = r*256 + t;               // 2304 float4s
    int h = f / 24, p4 = (f % 24) * 4;
    *(float4*)(as_ + h*100 + p4) =
        *(const float4*)(att + ((size_t)((b*H_ + h)*W_ + w)) * 192 + p4);
  }
  float acc[6][8] = {};              // h = ty+16a, c = c0+tx+16j
  for (int p0 = 0; p0 < 96; p0 += 16) {
    {
      int pp = t >> 4, c8 = (t & 15) * 8;
      uint4 u = *(const uint4*)(vp + ((size_t)(b*HW_ + (p0+pp)*W_ + w))*C_ + c0 + c8);
      float* d = vs + pp*128 + c8;
      d[0] = bf2f((u16)(u.x & 0xffff)); d[1] = bf2f((u16)(u.x >> 16));
      d[2] = bf2f((u16)(u.y & 0xffff)); d[3] = bf2f((u16)(u.y >> 16));
      d[4] = bf2f((u16)(u.z & 0xffff)); d[5] = bf2f((u16)(u.z >> 16));
      d[6] = bf2f((u16)(u.w & 0xffff)); d[7] = bf2f((u16)(u.w >> 16));
    }
    __syncthreads();
#pragma unroll
    for (int pp = 0; pp < 16; ++pp) {
      float av[6], vv[8];
#pragma unroll
      for (int a = 0; a < 6; ++a) av[a] = as_[(ty + 16*a)*100 + p0 + pp];
#pragma unroll
      for (int j = 0; j < 8; ++j) vv[j] = vs[pp*128 + tx + 16*j];
#pragma unroll
      for (int a = 0; a < 6; ++a)
#pragma unroll
        for (int j = 0; j < 8; ++j)
          acc[a][j] = fmaf(av[a], vv[j], acc[a][j]);
    }
    __syncthreads();
  }
  const float g = gammap[0];
#pragma unroll
  for (int a = 0; a < 6; ++a) {
    int h = ty + 16*a;
#pragma unroll
    for (int j = 0; j < 8; ++j) {
      int c = c0 + tx + 16*j;
      out[((size_t)(b*C_ + c)*H_ + h)*W_ + w] = g * acc[a][j];
    }
  }
}

// ---------------- outW + finalize: out += gamma * sum_p attW[w,p]*v[c,h,p] + x
__global__ __launch_bounds__(256) void outW_kernel(
    const float* __restrict__ att, const u16* __restrict__ vp,
    const float* __restrict__ x, const float* __restrict__ gammap,
    float* __restrict__ out)
{
  const int h = blockIdx.x, c0 = blockIdx.y * 128, b = blockIdx.z;
  __shared__ float as_[96*100];  // [w][p]
  __shared__ float vs[16*128];   // [pp][c]
  const int t = threadIdx.x;
  const int ty = t >> 4, tx = t & 15;
  for (int r = 0; r < 9; ++r) {
    int f = r*256 + t;
    int wl = f / 24, p4 = (f % 24) * 4;
    *(float4*)(as_ + wl*100 + p4) =
        *(const float4*)(att + ((size_t)((b*H_ + h)*W_ + wl)) * 192 + 96 + p4);
  }
  float acc[8][6] = {};              // c = c0+ty+16a, w = tx+16j
  for (int p0 = 0; p0 < 96; p0 += 16) {
    {
      int pp = t >> 4, c8 = (t & 15) * 8;
      uint4 u = *(const uint4*)(vp + ((size_t)(b*HW_ + h*W_ + p0 + pp))*C_ + c0 + c8);
      float* d = vs + pp*128 + c8;
      d[0] = bf2f((u16)(u.x & 0xffff)); d[1] = bf2f((u16)(u.x >> 16));
      d[2] = bf2f((u16)(u.y & 0xffff)); d[3] = bf2f((u16)(u.y >> 16));
      d[4] = bf2f((u16)(u.z & 0xffff)); d[5] = bf2f((u16)(u.z >> 16));
      d[6] = bf2f((u16)(u.w & 0xffff)); d[7] = bf2f((u16)(u.w >> 16));
    }
    __syncthreads();
#pragma unroll
    for (int pp = 0; pp < 16; ++pp) {
      float vv[8], aw[6];
#pragma unroll
      for (int a = 0; a < 8; ++a) vv[a] = vs[pp*128 + ty + 16*a];
#pragma unroll
      for (int j = 0; j < 6; ++j) aw[j] = as_[(tx + 16*j)*100 + p0 + pp];
#pragma unroll
      for (int a = 0; a < 8; ++a)
#pragma unroll
        for (int j = 0; j < 6; ++j)
          acc[a][j] = fmaf(vv[a], aw[j], acc[a][j]);
    }
    __syncthreads();
  }
  const float g = gammap[0];
#pragma unroll
  for (int a = 0; a < 8; ++a) {
    int c = c0 + ty + 16*a;
    size_t rowb = ((size_t)(b*C_ + c)*H_ + h)*W_;
#pragma unroll
    for (int j = 0; j < 6; ++j) {
      size_t idx = rowb + tx + 16*j;
      out[idx] = out[idx] + g*acc[a][j] + x[idx];
    }
  }
}

extern "C" void kernel_launch(void* const* d_in, const int* in_sizes, int n_in,
                              void* d_out, int out_size, void* d_ws, size_t ws_size,
                              hipStream_t stream) {
  const float* x     = (const float*)d_in[0];
  const float* Wq    = (const float*)d_in[1];
  const float* bq    = (const float*)d_in[2];
  const float* Wk    = (const float*)d_in[3];
  const float* bk    = (const float*)d_in[4];
  const float* Wv    = (const float*)d_in[5];
  const float* bv    = (const float*)d_in[6];
  const float* gamma = (const float*)d_in[7];
  float* out = (float*)d_out;

  char* ws = (char*)d_ws;
  float* qp  = (float*)ws;                                   // 18,874,368 B
  float* kp  = (float*)(ws + 18874368);                      // 18,874,368 B
  u16*   vp  = (u16*)  (ws + 2*18874368);                    // 75,497,472 B
  float* att = (float*)(ws + 2*18874368 + 75497472);         // 56,623,104 B  (total ~170 MB)

  dim3 blk(256);
  proj_kernel<float><<<dim3(HW_/64, 1, B_), blk, 0, stream>>>(x, Wq, bq, qp, CQ_);
  proj_kernel<float><<<dim3(HW_/64, 1, B_), blk, 0, stream>>>(x, Wk, bk, kp, CQ_);
  proj_kernel<u16>  <<<dim3(HW_/64, C_/64, B_), blk, 0, stream>>>(x, Wv, bv, vp, C_);
  score_col_kernel<<<dim3(W_, B_), blk, 0, stream>>>(qp, kp, att);
  score_row_kernel<<<dim3(H_, B_), blk, 0, stream>>>(qp, kp, att);
  softmax_kernel<<<dim3(NPIX_/4), blk, 0, stream>>>(att);
  outH_kernel<<<dim3(W_, C_/128, B_), blk, 0, stream>>>(att, vp, gamma, out);
  outW_kernel<<<dim3(H_, C_/128, B_), blk, 0, stream>>>(att, vp, x, gamma, out);
}

// Round 3
// 1010.402 us; speedup vs baseline: 1.7006x; 1.7006x over previous
//
#include <hip/hip_runtime.h>

#define B_   8
#define C_   512
#define H_   96
#define W_   96
#define HW_  (H_*W_)
#define NPIX_ (B_*HW_)

typedef unsigned short u16;
typedef __attribute__((ext_vector_type(8))) short short8;   // 8 bf16 = 4 VGPRs (MFMA A/B frag)
typedef __attribute__((ext_vector_type(4))) float f32x4;    // MFMA C/D frag
typedef __attribute__((address_space(1))) void as1_void;
typedef __attribute__((address_space(3))) void as3_void;

__device__ __forceinline__ float bf2f(u16 u) {
  unsigned int x = ((unsigned int)u) << 16;
  return __uint_as_float(x);
}
__device__ __forceinline__ u16 f2bf(float f) {
  unsigned int x = __float_as_uint(f);
  x += 0x7fffu + ((x >> 16) & 1u);   // RNE
  return (u16)(x >> 16);
}

// async global->LDS, 16 B per lane; LDS dest = wave-uniform base + lane*16
__device__ __forceinline__ void gld16(const void* g, void* l) {
  __builtin_amdgcn_global_load_lds((as1_void*)(const_cast<void*>(g)),
                                   (as3_void*)(l), 16, 0, 0);
}

// ---------------- prepass: x [b][c][hw] fp32 -> xT [b][pix][512] bf16
__global__ __launch_bounds__(256) void transpose_kernel(
    const float* __restrict__ x, u16* __restrict__ xT)
{
  const int p0 = blockIdx.x * 64, c0 = blockIdx.y * 64, b = blockIdx.z;
  __shared__ float tile[64*65];
  const int t = threadIdx.x;
  {
    const int cc = t >> 2, ps = (t & 3) * 16;
    const float* src = x + ((size_t)b*C_ + c0 + cc)*HW_ + p0 + ps;
    float4 f0 = *(const float4*)(src);
    float4 f1 = *(const float4*)(src + 4);
    float4 f2 = *(const float4*)(src + 8);
    float4 f3 = *(const float4*)(src + 12);
    float* d = tile + cc*65 + ps;
    d[0]=f0.x; d[1]=f0.y; d[2]=f0.z;  d[3]=f0.w;
    d[4]=f1.x; d[5]=f1.y; d[6]=f1.z;  d[7]=f1.w;
    d[8]=f2.x; d[9]=f2.y; d[10]=f2.z; d[11]=f2.w;
    d[12]=f3.x; d[13]=f3.y; d[14]=f3.z; d[15]=f3.w;
  }
  __syncthreads();
#pragma unroll
  for (int pass = 0; pass < 2; ++pass) {
    const int pr = pass*32 + (t >> 3), cs = (t & 7) * 8;
    union { u16 s[8]; uint4 v; } tmp;
#pragma unroll
    for (int i = 0; i < 8; ++i) tmp.s[i] = f2bf(tile[(cs + i)*65 + pr]);
    *(uint4*)(xT + ((size_t)b*HW_ + p0 + pr)*C_ + c0 + cs) = tmp.v;
  }
}

// ---------------- prepass: weights fp32 -> bf16.
// wdst layout (elems): [Wq 32768 | Wk 32768 | Wv 262144] = 327,680 elems
__global__ __launch_bounds__(256) void wconv_kernel(
    const float* __restrict__ Wq, const float* __restrict__ Wk,
    const float* __restrict__ Wv, u16* __restrict__ wdst)
{
  const int i = (blockIdx.x * 256 + threadIdx.x) * 4;
  const float* src; int off;
  if (i < 32768)      { src = Wq; off = 0; }
  else if (i < 65536) { src = Wk; off = 32768; }
  else                { src = Wv; off = 65536; }
  float4 f = *(const float4*)(src + (i - off));
  union { u16 s[4]; uint2 v; } o;
  o.s[0] = f2bf(f.x); o.s[1] = f2bf(f.y); o.s[2] = f2bf(f.z); o.s[3] = f2bf(f.w);
  *(uint2*)(wdst + i) = o.v;
}

__global__ __launch_bounds__(256) void wcopy_kernel(
    const uint4* __restrict__ s, uint4* __restrict__ d)
{
  const int i = blockIdx.x * 256 + threadIdx.x;
  d[i] = s[i];
}

// ---------------- MFMA projection GEMM:
// out[b][pix][ch] (bf16) = sum_c xT[b][pix][c]*Wt[ch][c] + bias[ch]
// grid (HW/128, NCH/128, nb), 256 threads = 4 waves, tile 128x128, BK=32
__global__ __launch_bounds__(256) void mfma_proj(
    const u16* __restrict__ xT, const u16* __restrict__ Wt,
    const float* __restrict__ bias0, const float* __restrict__ bias1,
    int split, int NCH, int b0, u16* __restrict__ outp)
{
  __shared__ __align__(16) u16 As[128*32];   // [pix][32k], rows 64 B, k-quads XOR-swizzled
  __shared__ __align__(16) u16 Bs[128*32];   // [ch][32k]
  const int b  = b0 + blockIdx.z;
  const int p0 = blockIdx.x * 128;
  const int n0 = blockIdx.y * 128;
  const int t = threadIdx.x;
  const int wv = t >> 6, lane = t & 63;
  const int wr = wv >> 1, wc = wv & 1;       // wave's 64x64 quadrant
  const int lhi = lane >> 4, llo = lane & 15;

  // staging: lane covers row = chunk*16 + (lane>>2), k-quad = (lane&3)^(row&3)
  const int srow = lane >> 2;
  const int skq  = (lane & 3) ^ (srow & 3);
  const u16* aG = xT + ((size_t)b*HW_ + p0 + srow) * C_ + skq * 8;
  const u16* bG = Wt + ((size_t)(n0 + srow)) * C_ + skq * 8;

  // frag read offsets (elems): quad q of row R sits at position q^(R&3)
  const int swz = (lhi ^ (llo & 3)) * 8;
  int aOff[4], bOff[4];
#pragma unroll
  for (int i = 0; i < 4; ++i) aOff[i] = (wr*64 + i*16 + llo)*32 + swz;
#pragma unroll
  for (int j = 0; j < 4; ++j) bOff[j] = (wc*64 + j*16 + llo)*32 + swz;

  f32x4 acc[4][4];
#pragma unroll
  for (int i = 0; i < 4; ++i)
#pragma unroll
    for (int j = 0; j < 4; ++j) acc[i][j] = (f32x4){0.f, 0.f, 0.f, 0.f};

  for (int k0 = 0; k0 < C_; k0 += 32) {
#pragma unroll
    for (int i = 0; i < 2; ++i) {
      const int chunk = wv*2 + i;            // wave-uniform
      gld16(aG + (size_t)chunk*16*C_ + k0, (void*)(As + chunk*512));
      gld16(bG + (size_t)chunk*16*C_ + k0, (void*)(Bs + chunk*512));
    }
    __syncthreads();                         // drains vmcnt before barrier
    short8 af[4], bfr[4];
#pragma unroll
    for (int i = 0; i < 4; ++i) af[i]  = *(const short8*)(As + aOff[i]);
#pragma unroll
    for (int j = 0; j < 4; ++j) bfr[j] = *(const short8*)(Bs + bOff[j]);
#pragma unroll
    for (int i = 0; i < 4; ++i)
#pragma unroll
      for (int j = 0; j < 4; ++j)
        acc[i][j] = __builtin_amdgcn_mfma_f32_16x16x32_bf16(af[i], bfr[j], acc[i][j], 0, 0, 0);
    __syncthreads();
  }

  // epilogue: D row (pix) = quad*4+reg, col (ch) = lane&15
#pragma unroll
  for (int j = 0; j < 4; ++j) {
    const int ch = n0 + wc*64 + j*16 + llo;
    const float bias = (ch < split) ? bias0[ch] : bias1[ch - split];
#pragma unroll
    for (int i = 0; i < 4; ++i) {
      const int pr = p0 + wr*64 + i*16 + lhi*4;
      u16* dst = outp + ((size_t)b*HW_ + pr) * NCH + ch;
#pragma unroll
      for (int r = 0; r < 4; ++r)
        dst[(size_t)r * NCH] = f2bf(acc[i][j][r] + bias);
    }
  }
}

// ---------------- eH logits: block per (w, b). qk bf16 [pix][128]: q=ch 0..63, k=ch 64..127
__global__ __launch_bounds__(256) void score_col_kernel(
    const u16* __restrict__ qk, float* __restrict__ att)
{
  const int w = blockIdx.x, b = blockIdx.y;
  __shared__ float qs[96*68];
  __shared__ float ks[96*68];
  const int t = threadIdx.x;
  for (int r = 0; r < 6; ++r) {
    int f = r*256 + t;                   // 1536 uint4 chunks
    int p = f >> 4, c8 = (f & 15) * 8;
    uint4 u = *(const uint4*)(qk + ((size_t)(b*HW_ + p*W_ + w))*128 + c8);
    float d[8];
    d[0]=bf2f(u.x & 0xffff); d[1]=bf2f(u.x >> 16);
    d[2]=bf2f(u.y & 0xffff); d[3]=bf2f(u.y >> 16);
    d[4]=bf2f(u.z & 0xffff); d[5]=bf2f(u.z >> 16);
    d[6]=bf2f(u.w & 0xffff); d[7]=bf2f(u.w >> 16);
    float* dst = (c8 < 64) ? (qs + p*68 + c8) : (ks + p*68 + (c8 - 64));
    *(float4*)(dst)     = make_float4(d[0], d[1], d[2], d[3]);
    *(float4*)(dst + 4) = make_float4(d[4], d[5], d[6], d[7]);
  }
  __syncthreads();
  const int ty = t >> 4, tx = t & 15;
  float e[6][6] = {};
#pragma unroll 8
  for (int c = 0; c < 64; ++c) {
    float qv[6], kv[6];
#pragma unroll
    for (int a = 0; a < 6; ++a) qv[a] = qs[(ty*6+a)*68 + c];
#pragma unroll
    for (int bb = 0; bb < 6; ++bb) kv[bb] = ks[(tx*6+bb)*68 + c];
#pragma unroll
    for (int a = 0; a < 6; ++a)
#pragma unroll
      for (int bb = 0; bb < 6; ++bb)
        e[a][bb] = fmaf(qv[a], kv[bb], e[a][bb]);
  }
#pragma unroll
  for (int a = 0; a < 6; ++a) {
    int h = ty*6 + a;
    size_t base = ((size_t)(b*H_ + h)*W_ + w) * 192;
#pragma unroll
    for (int bb = 0; bb < 6; ++bb) {
      int p = tx*6 + bb;
      att[base + p] = (h == p) ? -INFINITY : e[a][bb];
    }
  }
}

// ---------------- eW logits: block per (h, b)
__global__ __launch_bounds__(256) void score_row_kernel(
    const u16* __restrict__ qk, float* __restrict__ att)
{
  const int h = blockIdx.x, b = blockIdx.y;
  __shared__ float qs[96*68];
  __shared__ float ks[96*68];
  const int t = threadIdx.x;
  for (int r = 0; r < 6; ++r) {
    int f = r*256 + t;
    int p = f >> 4, c8 = (f & 15) * 8;
    uint4 u = *(const uint4*)(qk + ((size_t)(b*HW_ + h*W_ + p))*128 + c8);
    float d[8];
    d[0]=bf2f(u.x & 0xffff); d[1]=bf2f(u.x >> 16);
    d[2]=bf2f(u.y & 0xffff); d[3]=bf2f(u.y >> 16);
    d[4]=bf2f(u.z & 0xffff); d[5]=bf2f(u.z >> 16);
    d[6]=bf2f(u.w & 0xffff); d[7]=bf2f(u.w >> 16);
    float* dst = (c8 < 64) ? (qs + p*68 + c8) : (ks + p*68 + (c8 - 64));
    *(float4*)(dst)     = make_float4(d[0], d[1], d[2], d[3]);
    *(float4*)(dst + 4) = make_float4(d[4], d[5], d[6], d[7]);
  }
  __syncthreads();
  const int ty = t >> 4, tx = t & 15;
  float e[6][6] = {};
#pragma unroll 8
  for (int c = 0; c < 64; ++c) {
    float qv[6], kv[6];
#pragma unroll
    for (int a = 0; a < 6; ++a) qv[a] = qs[(ty*6+a)*68 + c];
#pragma unroll
    for (int bb = 0; bb < 6; ++bb) kv[bb] = ks[(tx*6+bb)*68 + c];
#pragma unroll
    for (int a = 0; a < 6; ++a)
#pragma unroll
      for (int bb = 0; bb < 6; ++bb)
        e[a][bb] = fmaf(qv[a], kv[bb], e[a][bb]);
  }
#pragma unroll
  for (int a = 0; a < 6; ++a) {
    int w = ty*6 + a;
    size_t base = ((size_t)(b*H_ + h)*W_ + w) * 192 + 96;
#pragma unroll
    for (int bb = 0; bb < 6; ++bb)
      att[base + tx*6 + bb] = e[a][bb];
  }
}

// ---------------- softmax over 192 logits per pixel; one wave per pixel
__global__ __launch_bounds__(256) void softmax_kernel(float* __restrict__ att)
{
  const int lane = threadIdx.x & 63;
  const int wv   = threadIdx.x >> 6;
  const size_t pix = (size_t)blockIdx.x * 4 + wv;
  float* row = att + pix * 192;
  float v0 = row[lane], v1 = row[lane+64], v2 = row[lane+128];
  float m = fmaxf(v0, fmaxf(v1, v2));
#pragma unroll
  for (int off = 32; off > 0; off >>= 1) m = fmaxf(m, __shfl_xor(m, off, 64));
  float e0 = __expf(v0 - m), e1 = __expf(v1 - m), e2 = __expf(v2 - m);
  float s = e0 + e1 + e2;
#pragma unroll
  for (int off = 32; off > 0; off >>= 1) s += __shfl_xor(s, off, 64);
  float inv = __frcp_rn(s);
  row[lane]     = e0 * inv;
  row[lane+64]  = e1 * inv;
  row[lane+128] = e2 * inv;
}

// ---------------- outH: block per (w, c_tile, b). out = gamma * sum_p attH[h,p]*v[c,p,w]
__global__ __launch_bounds__(256) void outH_kernel(
    const float* __restrict__ att, const u16* __restrict__ vp,
    const float* __restrict__ gammap, float* __restrict__ out)
{
  const int w = blockIdx.x, c0 = blockIdx.y * 128, b = blockIdx.z;
  __shared__ float as_[96*100];  // [h][p]
  __shared__ float vs[16*128];   // [pp][c]
  const int t = threadIdx.x;
  const int ty = t >> 4, tx = t & 15;
  for (int r = 0; r < 9; ++r) {
    int f = r*256 + t;
    int h = f / 24, p4 = (f % 24) * 4;
    *(float4*)(as_ + h*100 + p4) =
        *(const float4*)(att + ((size_t)((b*H_ + h)*W_ + w)) * 192 + p4);
  }
  float acc[6][8] = {};
  for (int p0 = 0; p0 < 96; p0 += 16) {
    {
      int pp = t >> 4, c8 = (t & 15) * 8;
      uint4 u = *(const uint4*)(vp + ((size_t)(b*HW_ + (p0+pp)*W_ + w))*C_ + c0 + c8);
      float* d = vs + pp*128 + c8;
      d[0] = bf2f((u16)(u.x & 0xffff)); d[1] = bf2f((u16)(u.x >> 16));
      d[2] = bf2f((u16)(u.y & 0xffff)); d[3] = bf2f((u16)(u.y >> 16));
      d[4] = bf2f((u16)(u.z & 0xffff)); d[5] = bf2f((u16)(u.z >> 16));
      d[6] = bf2f((u16)(u.w & 0xffff)); d[7] = bf2f((u16)(u.w >> 16));
    }
    __syncthreads();
#pragma unroll
    for (int pp = 0; pp < 16; ++pp) {
      float av[6], vv[8];
#pragma unroll
      for (int a = 0; a < 6; ++a) av[a] = as_[(ty + 16*a)*100 + p0 + pp];
#pragma unroll
      for (int j = 0; j < 8; ++j) vv[j] = vs[pp*128 + tx + 16*j];
#pragma unroll
      for (int a = 0; a < 6; ++a)
#pragma unroll
        for (int j = 0; j < 8; ++j)
          acc[a][j] = fmaf(av[a], vv[j], acc[a][j]);
    }
    __syncthreads();
  }
  const float g = gammap[0];
#pragma unroll
  for (int a = 0; a < 6; ++a) {
    int h = ty + 16*a;
#pragma unroll
    for (int j = 0; j < 8; ++j) {
      int c = c0 + tx + 16*j;
      out[((size_t)(b*C_ + c)*H_ + h)*W_ + w] = g * acc[a][j];
    }
  }
}

// ---------------- outW + finalize: out += gamma * sum_p attW[w,p]*v[c,h,p] + x
__global__ __launch_bounds__(256) void outW_kernel(
    const float* __restrict__ att, const u16* __restrict__ vp,
    const float* __restrict__ x, const float* __restrict__ gammap,
    float* __restrict__ out)
{
  const int h = blockIdx.x, c0 = blockIdx.y * 128, b = blockIdx.z;
  __shared__ float as_[96*100];  // [w][p]
  __shared__ float vs[16*128];   // [pp][c]
  const int t = threadIdx.x;
  const int ty = t >> 4, tx = t & 15;
  for (int r = 0; r < 9; ++r) {
    int f = r*256 + t;
    int wl = f / 24, p4 = (f % 24) * 4;
    *(float4*)(as_ + wl*100 + p4) =
        *(const float4*)(att + ((size_t)((b*H_ + h)*W_ + wl)) * 192 + 96 + p4);
  }
  float acc[8][6] = {};
  for (int p0 = 0; p0 < 96; p0 += 16) {
    {
      int pp = t >> 4, c8 = (t & 15) * 8;
      uint4 u = *(const uint4*)(vp + ((size_t)(b*HW_ + h*W_ + p0 + pp))*C_ + c0 + c8);
      float* d = vs + pp*128 + c8;
      d[0] = bf2f((u16)(u.x & 0xffff)); d[1] = bf2f((u16)(u.x >> 16));
      d[2] = bf2f((u16)(u.y & 0xffff)); d[3] = bf2f((u16)(u.y >> 16));
      d[4] = bf2f((u16)(u.z & 0xffff)); d[5] = bf2f((u16)(u.z >> 16));
      d[6] = bf2f((u16)(u.w & 0xffff)); d[7] = bf2f((u16)(u.w >> 16));
    }
    __syncthreads();
#pragma unroll
    for (int pp = 0; pp < 16; ++pp) {
      float vv[8], aw[6];
#pragma unroll
      for (int a = 0; a < 8; ++a) vv[a] = vs[pp*128 + ty + 16*a];
#pragma unroll
      for (int j = 0; j < 6; ++j) aw[j] = as_[(tx + 16*j)*100 + p0 + pp];
#pragma unroll
      for (int a = 0; a < 8; ++a)
#pragma unroll
        for (int j = 0; j < 6; ++j)
          acc[a][j] = fmaf(vv[a], aw[j], acc[a][j]);
    }
    __syncthreads();
  }
  const float g = gammap[0];
#pragma unroll
  for (int a = 0; a < 8; ++a) {
    int c = c0 + ty + 16*a;
    size_t rowb = ((size_t)(b*C_ + c)*H_ + h)*W_;
#pragma unroll
    for (int j = 0; j < 6; ++j) {
      size_t idx = rowb + tx + 16*j;
      out[idx] = out[idx] + g*acc[a][j] + x[idx];
    }
  }
}

extern "C" void kernel_launch(void* const* d_in, const int* in_sizes, int n_in,
                              void* d_out, int out_size, void* d_ws, size_t ws_size,
                              hipStream_t stream) {
  const float* x     = (const float*)d_in[0];
  const float* Wq    = (const float*)d_in[1];
  const float* bq    = (const float*)d_in[2];
  const float* Wk    = (const float*)d_in[3];
  const float* bk    = (const float*)d_in[4];
  const float* Wv    = (const float*)d_in[5];
  const float* bv    = (const float*)d_in[6];
  const float* gamma = (const float*)d_in[7];
  float* out = (float*)d_out;
  char* ws = (char*)d_ws;

  // ws layout (169,869,312 B total):
  //   region0 @0        : xT bf16 [B][HW][512] (75,497,472 B) -> reused as att fp32 (56,623,104 B)
  //   qk      @75497472 : bf16 [B][HW][128] (18,874,368 B); weights parked at its base pre-proj
  //   vp      @94371840 : bf16 [B][HW][512] (75,497,472 B)
  u16*   xT    = (u16*)ws;
  float* att   = (float*)ws;
  u16*   qk    = (u16*)(ws + 75497472);
  u16*   vp    = (u16*)(ws + 94371840);
  u16*   wpark = qk;                       // [Wq 32768 | Wk 32768 | Wv 262144] bf16 = 655,360 B
  u16*   wvbf  = wpark + 65536;            // Wv starts after Wq|Wk (65,536 elems)
  u16*   wqk0  = (u16*)(ws + 75366400);    // Wqk relocation target: last 131,072 B of region0

  dim3 blk(256);
  wconv_kernel<<<320, blk, 0, stream>>>(Wq, Wk, Wv, wpark);
  transpose_kernel<<<dim3(HW_/64, C_/64, B_), blk, 0, stream>>>(x, xT);
  // q,k fused proj for batches 1..7 (their qk region doesn't overlap parked weights)
  mfma_proj<<<dim3(HW_/128, 1, 7), blk, 0, stream>>>(xT, wpark, bq, bk, 64, 128, 1, qk);
  // v proj, all batches
  mfma_proj<<<dim3(HW_/128, 4, 8), blk, 0, stream>>>(xT, wvbf, bv, bv, 512, 512, 0, vp);
  // xT batch 7 tail now dead -> relocate Wqk there (131,072 B = 8192 uint4), then batch-0 qk proj
  wcopy_kernel<<<32, blk, 0, stream>>>((const uint4*)wpark, (uint4*)wqk0);
  mfma_proj<<<dim3(HW_/128, 1, 1), blk, 0, stream>>>(xT, wqk0, bq, bk, 64, 128, 0, qk);
  score_col_kernel<<<dim3(W_, B_), blk, 0, stream>>>(qk, att);
  score_row_kernel<<<dim3(H_, B_), blk, 0, stream>>>(qk, att);
  softmax_kernel<<<dim3(NPIX_/4), blk, 0, stream>>>(att);
  outH_kernel<<<dim3(W_, C_/128, B_), blk, 0, stream>>>(att, vp, gamma, out);
  outW_kernel<<<dim3(H_, C_/128, B_), blk, 0, stream>>>(att, vp, x, gamma, out);
}